// Round 18
// baseline (1139.468 us; speedup 1.0000x reference)
//
#include <hip/hip_runtime.h>
#include <cstdint>
#include <type_traits>

#define B_    8
#define T_    2048
#define C_    1024
#define E_    8
#define K_    2
#define CAP_  4096
#define H_    4096
#define NTOK  (B_ * T_)      // 16384
#define NSLOT (NTOK * K_)    // 32768
#define KR_   3072           // exact router split-GEMM K: [x_hi | x_lo | x_hi]

typedef __bf16 bf16x8 __attribute__((ext_vector_type(8)));
typedef float  f32x4  __attribute__((ext_vector_type(4)));

#define AS1 __attribute__((address_space(1)))
#define AS3 __attribute__((address_space(3)))

static __device__ __forceinline__ float b2f(unsigned short u) {
    union { float f; unsigned int i; } v; v.i = ((unsigned int)u) << 16; return v.f;
}
static __device__ __forceinline__ unsigned short f2b(float f) {
    unsigned int x = __float_as_uint(f);
    unsigned int r = (x + 0x7fffu + ((x >> 16) & 1u)) >> 16;   // RNE
    return (unsigned short)r;
}

template<int W> static __device__ __forceinline__ void vm_wait() {
    if constexpr (W == 4) asm volatile("s_waitcnt vmcnt(4)" ::: "memory");
    else if constexpr (W == 0) asm volatile("s_waitcnt vmcnt(0)" ::: "memory");
}

// ---------------------------------------------------------------------------
// Expert GEMM kernel, NEW geometry for cross-block overlap: 256 threads
// (4 waves, 2Mx2N, wave tile 64x128), tile 128x256, BK=32, dbuf LDS
// 2 x (A 8KB + B 16KB) = 48KB -> 2 BLOCKS PER CU (launch_bounds(256,2):
// VGPR cap 256; acc 128 + frags ~50 -> no spill, unlike round-7's 4-wave
// forcing). The two co-resident blocks have INDEPENDENT barriers -> one
// block's MFMA burst overlaps the other's LDS/stage/drain phase (m114
// mechanism) — the lockstep that pinned MfmaUtil at 38-45% for rounds
// 6-17 is broken without changing waves/SIMD.
// K-loop ledger = round-6 proven: STAGE(t+1); COMPUTE(t); vmcnt(0);
// barrier (drain hidden by the other block). Swizzle for 64B rows:
// slot(16B) ^= row&3 (both sides) -> 2-way bank aliasing (free, m136).
// A [M][Kd] bf16 row-major, BT [N][Kd] bf16 (pre-transposed). Out [M][Nld].
// Requires M%128==0, N%256==0, Kd%32==0, grid.x*grid.y%8==0.
// ---------------------------------------------------------------------------
template<int RELU, typename TC>
__global__ __launch_bounds__(256, 2) void gemm128n(
    const unsigned short* __restrict__ A, const unsigned short* __restrict__ BT,
    const float* __restrict__ bias, TC* __restrict__ Cout,
    int Kd, int Nld, int NT,
    long sA, long sB, long sBias, long sC)
{
    extern __shared__ char smem[];   // dbuf d: A at d*24576, B at +8192

    const int z = blockIdx.z;
    A    += (size_t)z * sA;
    BT   += (size_t)z * sB;
    bias += (size_t)z * sBias;
    Cout += (size_t)z * sC;

    // XCD-aware swizzle (nwg % 8 == 0 for all our grids)
    const int gx = gridDim.x;
    const int nwg = gx * gridDim.y;
    int wg = blockIdx.y * gx + blockIdx.x;
    wg = (wg & 7) * (nwg >> 3) + (wg >> 3);
    const int bm = (wg / gx) * 128;
    const int bn = (wg % gx) * 256;

    const int tid  = threadIdx.x;
    const int lane = tid & 63;
    const int wid  = tid >> 6;
    const int wrow = (wid >> 1) * 64;    // wave M offset (2 waves in M)
    const int wcol = (wid & 1) * 128;    // wave N offset (2 waves in N)
    const int fr = lane & 15;            // fragment row/col within 16
    const int fq = lane >> 4;            // k-chunk selector (0..3)

    const size_t rbA = (size_t)Kd * 2;   // row stride in bytes (A and BT)
    const char* Ag = (const char*)A  + (size_t)bm * rbA;
    const char* Bg = (const char*)BT + (size_t)bn * rbA;

    f32x4 acc[4][8];
#pragma unroll
    for (int i = 0; i < 4; i++)
#pragma unroll
        for (int j = 0; j < 8; j++) acc[i][j] = (f32x4){0.f, 0.f, 0.f, 0.f};

    // stage K-tile kt (A 8KB: 2 rounds; B 16KB: 4 rounds; 64B rows,
    // source slot pre-swizzled so swizzled ds_reads see linear data)
    auto STAGE = [&](int kt) {
        char* dA = smem + (size_t)(kt & 1) * 24576;
        char* dB = dA + 8192;
        const size_t kb = (size_t)kt * 64;
#pragma unroll
        for (int r = 0; r < 2; ++r) {
            const int o    = r * 4096 + tid * 16;
            const int row  = o >> 6;
            const int slot = (o >> 4) & 3;
            const int ss   = (slot ^ (row & 3)) << 4;
            __builtin_amdgcn_global_load_lds(
                (const AS1 void*)(Ag + (size_t)row * rbA + kb + ss),
                (AS3 void*)(dA + r * 4096 + wid * 1024), 16, 0, 0);
        }
#pragma unroll
        for (int r = 0; r < 4; ++r) {
            const int o    = r * 4096 + tid * 16;
            const int row  = o >> 6;
            const int slot = (o >> 4) & 3;
            const int ss   = (slot ^ (row & 3)) << 4;
            __builtin_amdgcn_global_load_lds(
                (const AS1 void*)(Bg + (size_t)row * rbA + kb + ss),
                (AS3 void*)(dB + r * 4096 + wid * 1024), 16, 0, 0);
        }
    };

    auto COMPUTE = [&](int kt) {
        const char* bufA = smem + (size_t)(kt & 1) * 24576;
        const char* bufB = bufA + 8192;
        bf16x8 a_[4], b_[8];
#pragma unroll
        for (int mi = 0; mi < 4; ++mi) {
            const int row = wrow + mi * 16 + fr;
            a_[mi] = *(const bf16x8*)(bufA + row * 64 + ((fq ^ (row & 3)) << 4));
        }
#pragma unroll
        for (int ni = 0; ni < 8; ++ni) {
            const int row = wcol + ni * 16 + fr;
            b_[ni] = *(const bf16x8*)(bufB + row * 64 + ((fq ^ (row & 3)) << 4));
        }
        __builtin_amdgcn_s_setprio(1);
#pragma unroll
        for (int mi = 0; mi < 4; ++mi)
#pragma unroll
            for (int ni = 0; ni < 8; ++ni)
                acc[mi][ni] = __builtin_amdgcn_mfma_f32_16x16x32_bf16(
                    a_[mi], b_[ni], acc[mi][ni], 0, 0, 0);
        __builtin_amdgcn_s_setprio(0);
    };

    // prologue
    STAGE(0);
    vm_wait<0>();
    __builtin_amdgcn_s_barrier();

    // main loop (round-6 ledger: WAR safe — slot (t+1)&1 last read in
    // COMPUTE(t-1), completed before previous barrier; RAW via vmcnt(0)).
    for (int kt = 0; kt < NT - 1; ++kt) {
        STAGE(kt + 1);
        COMPUTE(kt);
        vm_wait<0>();
        __builtin_amdgcn_s_barrier();
    }
    COMPUTE(NT - 1);

    // epilogue (16x16 C/D: col=lane&15, row=fq*4+reg — round-6 proven map)
    const float* bias_o = bias;
    asm volatile("" : "+s"(bias_o));
#pragma unroll
    for (int mi = 0; mi < 4; ++mi) {
#pragma unroll
        for (int ni = 0; ni < 8; ++ni) {
            const int c = bn + wcol + ni * 16 + fr;
            const float bv = bias_o[c];
#pragma unroll
            for (int rg = 0; rg < 4; ++rg) {
                const int r = bm + wrow + mi * 16 + fq * 4 + rg;
                float v = acc[mi][ni][rg] + bv;
                if (RELU) v = fmaxf(v, 0.f);
                if constexpr (std::is_same_v<TC, float>)
                    Cout[(size_t)r * Nld + c] = v;
                else
                    Cout[(size_t)r * Nld + c] = f2b(v);
            }
        }
    }
}

// ---------------------------------------------------------------------------
// Router GEMM (round-15/17 proven): 256x256 tile, BK=64, 512 thr, 8-phase,
// counted vmcnt(4), segment-remapped sources, fused-logits epilogue (EPI3).
// ---------------------------------------------------------------------------
template<int RELU, typename TC, int EPI>
__global__ __launch_bounds__(512, 2) void gemm256_8ph(
    const unsigned short* __restrict__ A, const unsigned short* __restrict__ BT,
    const float* __restrict__ bias, TC* __restrict__ Cout,
    int Kd, int Nld, int NT,
    long rabA, long rabB, long thrA, long thrB,
    long sA, long sB, long sBias, long sC,
    const float* __restrict__ rw2v, float* __restrict__ plogv)
{
    extern __shared__ char smem[];

    const int z = blockIdx.z;
    A    += (size_t)z * sA;
    BT   += (size_t)z * sB;
    bias += (size_t)z * sBias;
    if constexpr (EPI == 0) Cout += (size_t)z * sC;

    const int gx = gridDim.x;
    const int nwg = gx * gridDim.y;
    int wg = blockIdx.y * gx + blockIdx.x;
    wg = (wg & 7) * (nwg >> 3) + (wg >> 3);
    const int bm = (wg / gx) * 256;
    const int bn = (wg % gx) * 256;

    const int tid  = threadIdx.x;
    const int lane = tid & 63;
    const int wid  = tid >> 6;
    const int wrow = (wid >> 2) * 128;
    const int wcol = (wid & 3) * 64;
    const int fr = lane & 15;
    const int fq = lane >> 4;

    const char* Ag = (const char*)A  + (size_t)bm * rabA;
    const char* Bg = (const char*)BT + (size_t)bn * rabB;

    f32x4 acc[8][4];
#pragma unroll
    for (int i = 0; i < 8; i++)
#pragma unroll
        for (int j = 0; j < 4; j++) acc[i][j] = (f32x4){0.f, 0.f, 0.f, 0.f};

    auto STAGE_A = [&](int kt) {
        char* d = smem + (size_t)(kt & 1) * 65536;
        long kb = (long)kt * 128;
        if (kb >= thrA) kb -= thrA;
#pragma unroll
        for (int r = 0; r < 4; ++r) {
            const int o    = r * 8192 + tid * 16;
            const int row  = o >> 7;
            const int slot = (o >> 4) & 7;
            const int ss   = (slot ^ (row & 7)) << 4;
            __builtin_amdgcn_global_load_lds(
                (const AS1 void*)(Ag + (size_t)row * rabA + kb + ss),
                (AS3 void*)(d + r * 8192 + wid * 1024), 16, 0, 0);
        }
    };
    auto STAGE_B = [&](int kt) {
        char* d = smem + (size_t)(kt & 1) * 65536 + 32768;
        long kb = (long)kt * 128;
        if (kb >= thrB) kb -= thrB;
#pragma unroll
        for (int r = 0; r < 4; ++r) {
            const int o    = r * 8192 + tid * 16;
            const int row  = o >> 7;
            const int slot = (o >> 4) & 7;
            const int ss   = (slot ^ (row & 7)) << 4;
            __builtin_amdgcn_global_load_lds(
                (const AS1 void*)(Bg + (size_t)row * rabB + kb + ss),
                (AS3 void*)(d + r * 8192 + wid * 1024), 16, 0, 0);
        }
    };

    auto LDA = [&](int kt, int mi, int kk) -> bf16x8 {
        const char* base = smem + (size_t)(kt & 1) * 65536;
        const int row  = wrow + mi * 16 + fr;
        const int slot = (kk * 4 + fq) ^ (row & 7);
        return *(const bf16x8*)(base + row * 128 + slot * 16);
    };
    auto LDB = [&](int kt, int ni, int kk) -> bf16x8 {
        const char* base = smem + (size_t)(kt & 1) * 65536 + 32768;
        const int row  = wcol + ni * 16 + fr;
        const int slot = (kk * 4 + fq) ^ (row & 7);
        return *(const bf16x8*)(base + row * 128 + slot * 16);
    };

    STAGE_A(0); STAGE_B(0); STAGE_B(1);
    vm_wait<4>();
    __builtin_amdgcn_s_barrier();

    bf16x8 a[4], bb[4];
    for (int kt = 0; kt < NT; ++kt) {
#pragma unroll
        for (int i = 0; i < 4; ++i) a[i]  = LDA(kt, i, 0);
#pragma unroll
        for (int i = 0; i < 4; ++i) bb[i] = LDB(kt, i, 0);
        if (kt + 1 < NT) STAGE_A(kt + 1);
        __builtin_amdgcn_s_barrier();
        __builtin_amdgcn_s_setprio(1);
#pragma unroll
        for (int mi = 0; mi < 4; ++mi)
#pragma unroll
            for (int ni = 0; ni < 4; ++ni)
                acc[mi][ni] = __builtin_amdgcn_mfma_f32_16x16x32_bf16(
                    a[mi], bb[ni], acc[mi][ni], 0, 0, 0);
        __builtin_amdgcn_s_setprio(0);
        __builtin_amdgcn_s_barrier();
#pragma unroll
        for (int i = 0; i < 4; ++i) a[i] = LDA(kt, 4 + i, 0);
        __builtin_amdgcn_s_barrier();
        __builtin_amdgcn_s_setprio(1);
#pragma unroll
        for (int mi = 0; mi < 4; ++mi)
#pragma unroll
            for (int ni = 0; ni < 4; ++ni)
                acc[4 + mi][ni] = __builtin_amdgcn_mfma_f32_16x16x32_bf16(
                    a[mi], bb[ni], acc[4 + mi][ni], 0, 0, 0);
        __builtin_amdgcn_s_setprio(0);
        __builtin_amdgcn_s_barrier();
#pragma unroll
        for (int i = 0; i < 4; ++i) a[i]  = LDA(kt, i, 1);
#pragma unroll
        for (int i = 0; i < 4; ++i) bb[i] = LDB(kt, i, 1);
        __builtin_amdgcn_s_barrier();
        __builtin_amdgcn_s_setprio(1);
#pragma unroll
        for (int mi = 0; mi < 4; ++mi)
#pragma unroll
            for (int ni = 0; ni < 4; ++ni)
                acc[mi][ni] = __builtin_amdgcn_mfma_f32_16x16x32_bf16(
                    a[mi], bb[ni], acc[mi][ni], 0, 0, 0);
        __builtin_amdgcn_s_setprio(0);
        __builtin_amdgcn_s_barrier();
#pragma unroll
        for (int i = 0; i < 4; ++i) a[i] = LDA(kt, 4 + i, 1);
        if (kt + 2 < NT) STAGE_B(kt + 2);
        if (kt + 1 < NT) {
            if (kt + 2 < NT) vm_wait<4>();
            else             vm_wait<0>();
        }
        __builtin_amdgcn_s_barrier();
        __builtin_amdgcn_s_setprio(1);
#pragma unroll
        for (int mi = 0; mi < 4; ++mi)
#pragma unroll
            for (int ni = 0; ni < 4; ++ni)
                acc[4 + mi][ni] = __builtin_amdgcn_mfma_f32_16x16x32_bf16(
                    a[mi], bb[ni], acc[4 + mi][ni], 0, 0, 0);
        __builtin_amdgcn_s_setprio(0);
        __builtin_amdgcn_s_barrier();
    }

    const float* bias_o = bias;
    asm volatile("" : "+s"(bias_o));

    if constexpr (EPI == 3) {
        float w2r[4][8];
#pragma unroll
        for (int ni = 0; ni < 4; ++ni) {
            const float* src = rw2v + (size_t)(bn + wcol + ni * 16 + fr) * 8;
            *(float4*)(w2r[ni])     = *(const float4*)(src);
            *(float4*)(w2r[ni] + 4) = *(const float4*)(src + 4);
        }
        float bv[4];
#pragma unroll
        for (int ni = 0; ni < 4; ++ni)
            bv[ni] = bias_o[bn + wcol + ni * 16 + fr];

        float* pb = (float*)smem;
        const int rowhalf = wid >> 2, colwave = wid & 3;
        const int frq = fr >> 2;

#pragma unroll
        for (int mi = 0; mi < 8; ++mi) {
#pragma unroll
            for (int rg = 0; rg < 4; ++rg) {
                float p[8];
#pragma unroll
                for (int e = 0; e < 8; ++e) p[e] = 0.f;
#pragma unroll
                for (int ni = 0; ni < 4; ++ni) {
                    const float h = fmaxf(acc[mi][ni][rg] + bv[ni], 0.f);
#pragma unroll
                    for (int e = 0; e < 8; ++e) p[e] = fmaf(h, w2r[ni][e], p[e]);
                }
#pragma unroll
                for (int e = 0; e < 8; ++e) {
                    p[e] += __shfl_xor(p[e], 1);
                    p[e] += __shfl_xor(p[e], 2);
                }
                if ((fr & 3) == 0) {
                    const int row = mi * 16 + fq * 4 + rg;
                    float* dst = pb +
                        ((((size_t)rowhalf * 4 + colwave) * 128 + row) * 4 + frq) * 8;
                    *(float4*)(dst)     = make_float4(p[0], p[1], p[2], p[3]);
                    *(float4*)(dst + 4) = make_float4(p[4], p[5], p[6], p[7]);
                }
            }
        }
        __syncthreads();
        {
            const int r  = tid >> 1;
            const int eh = (tid & 1) * 4;
            const int rowhalf2 = r >> 7, rl = r & 127;
            float4 s = make_float4(0.f, 0.f, 0.f, 0.f);
#pragma unroll
            for (int cw = 0; cw < 4; ++cw)
#pragma unroll
                for (int q = 0; q < 4; ++q) {
                    const float4 v = *(const float4*)(pb +
                        ((((size_t)rowhalf2 * 4 + cw) * 128 + rl) * 4 + q) * 8 + eh);
                    s.x += v.x; s.y += v.y; s.z += v.z; s.w += v.w;
                }
            *(float4*)(plogv + ((size_t)(bn >> 8) * NTOK + bm + r) * 8 + eh) = s;
        }
    } else {
#pragma unroll
        for (int mi = 0; mi < 8; ++mi) {
#pragma unroll
            for (int ni = 0; ni < 4; ++ni) {
                const int c = bn + wcol + ni * 16 + fr;
                const float bv = bias_o[c];
#pragma unroll
                for (int rg = 0; rg < 4; ++rg) {
                    const int r = bm + wrow + mi * 16 + fq * 4 + rg;
                    float v = acc[mi][ni][rg] + bv;
                    if (RELU) v = fmaxf(v, 0.f);
                    if constexpr (std::is_same_v<TC, float>)
                        Cout[(size_t)r * Nld + c] = v;
                    else
                        Cout[(size_t)r * Nld + c] = f2b(v);
                }
            }
        }
    }
}

// ---------------------------------------------------------------------------
__global__ __launch_bounds__(256) void router_topk_final(
    const float* __restrict__ plog, const float* __restrict__ rb2,
    int* __restrict__ ids, float* __restrict__ probs)
{
    const int n = blockIdx.x * 256 + threadIdx.x;
    float l[E_];
#pragma unroll
    for (int e = 0; e < E_; ++e) l[e] = rb2[e];
#pragma unroll
    for (int bx = 0; bx < 16; ++bx) {
        const float4 a = *(const float4*)(plog + ((size_t)bx * NTOK + n) * 8);
        const float4 b = *(const float4*)(plog + ((size_t)bx * NTOK + n) * 8 + 4);
        l[0] += a.x; l[1] += a.y; l[2] += a.z; l[3] += a.w;
        l[4] += b.x; l[5] += b.y; l[6] += b.z; l[7] += b.w;
    }
    float v1 = -1e30f, v2 = -1e30f; int i1 = 0, i2 = 0;
#pragma unroll
    for (int e = 0; e < E_; ++e) {
        const float v = l[e];
        if (v > v1)      { v2 = v1; i2 = i1; v1 = v; i1 = e; }
        else if (v > v2) { v2 = v;  i2 = e; }
    }
    const float e2 = expf(v2 - v1);
    const float inv = 1.f / (1.f + e2);
    ids[n * 2] = i1;  ids[n * 2 + 1] = i2;
    probs[n * 2] = inv; probs[n * 2 + 1] = e2 * inv;
}

// ---------------------------------------------------------------------------
__global__ __launch_bounds__(256) void split_x(
    const float* __restrict__ x, unsigned short* __restrict__ A2)
{
    const int n = blockIdx.x;
    const int c = threadIdx.x * 4;
    const float4 v = *(const float4*)(x + (size_t)n * C_ + c);
    ushort4 hi, lo;
    hi.x = f2b(v.x); lo.x = f2b(v.x - b2f(hi.x));
    hi.y = f2b(v.y); lo.y = f2b(v.y - b2f(hi.y));
    hi.z = f2b(v.z); lo.z = f2b(v.z - b2f(hi.z));
    hi.w = f2b(v.w); lo.w = f2b(v.w - b2f(hi.w));
    unsigned short* row = A2 + (size_t)n * 2048;
    *(ushort4*)(row + c)        = hi;
    *(ushort4*)(row + C_ + c)   = lo;
}

// ---------------------------------------------------------------------------
__global__ __launch_bounds__(256) void split_w(
    const float* __restrict__ in, unsigned short* __restrict__ out)
{
    __shared__ float t[32][33];
    const int rb = blockIdx.y * 32;
    const int cb = blockIdx.x * 32;
    const int tr = threadIdx.x >> 3, tc = (threadIdx.x & 7) * 4;
    const float4 v = *(const float4*)(in + (size_t)(rb + tr) * H_ + cb + tc);
    t[tr][tc + 0] = v.x; t[tr][tc + 1] = v.y; t[tr][tc + 2] = v.z; t[tr][tc + 3] = v.w;
    __syncthreads();
    ushort4 hi, lo;
    float f;
    f = t[tc + 0][tr]; hi.x = f2b(f); lo.x = f2b(f - b2f(hi.x));
    f = t[tc + 1][tr]; hi.y = f2b(f); lo.y = f2b(f - b2f(hi.y));
    f = t[tc + 2][tr]; hi.z = f2b(f); lo.z = f2b(f - b2f(hi.z));
    f = t[tc + 3][tr]; hi.w = f2b(f); lo.w = f2b(f - b2f(hi.w));
    unsigned short* row = out + (size_t)(cb + tr) * 2048;
    *(ushort4*)(row + rb + tc)        = hi;
    *(ushort4*)(row + C_ + rb + tc)   = lo;
}

// ---------------------------------------------------------------------------
__global__ __launch_bounds__(256) void transpose_cvt(
    const float* __restrict__ in, unsigned short* __restrict__ out, int R, int Ncols)
{
    __shared__ float t[32][33];
    const size_t zoff = (size_t)blockIdx.z * R * Ncols;
    in  += zoff;
    out += zoff;
    const int rb = blockIdx.y * 32, cb = blockIdx.x * 32;
    const int tr = threadIdx.x >> 3, tc = (threadIdx.x & 7) * 4;
    const float4 v = *(const float4*)(in + (size_t)(rb + tr) * Ncols + cb + tc);
    t[tr][tc + 0] = v.x; t[tr][tc + 1] = v.y; t[tr][tc + 2] = v.z; t[tr][tc + 3] = v.w;
    __syncthreads();
    ushort4 u;
    u.x = f2b(t[tc + 0][tr]); u.y = f2b(t[tc + 1][tr]);
    u.z = f2b(t[tc + 2][tr]); u.w = f2b(t[tc + 3][tr]);
    *(ushort4*)(out + (size_t)(cb + tr) * R + rb + tc) = u;
}

// ---------------------------------------------------------------------------
// Exact sequential per-expert prefix count (parallel scan, same semantics).
// ---------------------------------------------------------------------------
__global__ __launch_bounds__(1024) void compute_pos(
    const int* __restrict__ ids, int* __restrict__ pos)
{
    __shared__ int hist[1024][E_];
    const int t = threadIdx.x;
    const int per = NSLOT / 1024;    // 32
    int cnt[E_];
#pragma unroll
    for (int e = 0; e < E_; e++) cnt[e] = 0;
    const int s0 = t * per;
    for (int i = 0; i < per; i++) cnt[ids[s0 + i]]++;
#pragma unroll
    for (int e = 0; e < E_; e++) hist[t][e] = cnt[e];
    __syncthreads();
    const int wv = t >> 6, ln = t & 63;
    if (wv < E_) {
        const int e = wv;
        const int base = ln * 16;
        int vals[16];
        int s = 0;
#pragma unroll
        for (int i = 0; i < 16; i++) vals[i] = hist[base + i][e];
#pragma unroll
        for (int i = 0; i < 16; i++) { const int v = vals[i]; vals[i] = s; s += v; }
        int x = s;
        for (int d = 1; d < 64; d <<= 1) {
            const int y = __shfl_up(x, d);
            if (ln >= d) x += y;
        }
        const int excl = x - s;
#pragma unroll
        for (int i = 0; i < 16; i++) hist[base + i][e] = vals[i] + excl;
    }
    __syncthreads();
    int run[E_];
#pragma unroll
    for (int e = 0; e < E_; e++) run[e] = hist[t][e];
    for (int i = 0; i < per; i++) { const int e = ids[s0 + i]; pos[s0 + i] = run[e]++; }
}

// ---------------------------------------------------------------------------
__global__ __launch_bounds__(256) void dispatch_k(
    const float* __restrict__ x, const int* __restrict__ ids,
    const int* __restrict__ pos, unsigned short* __restrict__ disp)
{
    const int s = blockIdx.x;
    const int e = ids[s], p = pos[s];
    if (p >= CAP_) return;
    const int n = s >> 1;
    const float4 v = *(const float4*)(x + (size_t)n * C_ + threadIdx.x * 4);
    ushort4 u;
    u.x = f2b(v.x); u.y = f2b(v.y); u.z = f2b(v.z); u.w = f2b(v.w);
    *(ushort4*)(disp + ((size_t)e * CAP_ + p) * C_ + threadIdx.x * 4) = u;
}

// ---------------------------------------------------------------------------
__global__ __launch_bounds__(256) void combine_k(
    const unsigned short* __restrict__ eo, const int* __restrict__ ids,
    const int* __restrict__ pos, const float* __restrict__ probs,
    float* __restrict__ y)
{
    const int n = blockIdx.x;
    const int c = threadIdx.x * 4;
    float r0 = 0.f, r1 = 0.f, r2 = 0.f, r3 = 0.f;
#pragma unroll
    for (int k = 0; k < K_; k++) {
        const int p = pos[2 * n + k];
        if (p >= CAP_) continue;
        const int e = ids[2 * n + k];
        const float w = probs[2 * n + k];
        const ushort4 u = *(const ushort4*)(eo + ((size_t)e * CAP_ + p) * C_ + c);
        r0 = fmaf(w, b2f(u.x), r0); r1 = fmaf(w, b2f(u.y), r1);
        r2 = fmaf(w, b2f(u.z), r2); r3 = fmaf(w, b2f(u.w), r3);
    }
    *(float4*)(y + (size_t)n * C_ + c) = make_float4(r0, r1, r2, r3);
}

// ---------------------------------------------------------------------------
extern "C" void kernel_launch(void* const* d_in, const int* in_sizes, int n_in,
                              void* d_out, int out_size, void* d_ws, size_t ws_size,
                              hipStream_t stream)
{
    const float* x   = (const float*)d_in[0];
    const float* rw1 = (const float*)d_in[1];
    const float* rb1 = (const float*)d_in[2];
    const float* rw2 = (const float*)d_in[3];
    const float* rb2 = (const float*)d_in[4];
    const float* ew1 = (const float*)d_in[5];
    const float* eb1 = (const float*)d_in[6];
    const float* ew2 = (const float*)d_in[7];
    const float* eb2 = (const float*)d_in[8];
    float* y = (float*)d_out;

    // ws layout (r17 evidenced):
    //  [0,256MiB)      hexp bf16 [8][4096][4096]
    //  [256,320MiB)    A2' bf16 [16384][2048] (router) -> later disp -> eo
    //  [320,384MiB)    BTW expert weights (written at 5a; A2'/B2'/plog dead)
    //  [352,360MiB)    B2' bf16 [4096][2048] (router; time-disjoint with BTW)
    //  [376,384MiB)    plog f32 [16][16384][8]
    //  [384MiB,...)    ids / probs / pos
    char* ws = (char*)d_ws;
    unsigned short* hexp  = (unsigned short*)ws;
    unsigned short* A2    = (unsigned short*)(ws + 268435456L);
    unsigned short* disp  = (unsigned short*)(ws + 268435456L);
    unsigned short* eo    = (unsigned short*)(ws + 268435456L);
    unsigned short* BTW   = (unsigned short*)(ws + 335544320L);
    unsigned short* B2    = (unsigned short*)(ws + 369098752L);
    float*          plog  = (float*)(ws + 394264576L);
    int*            ids   = (int*)  (ws + 402653184L);
    float*          probs = (float*)(ws + 402784256L);
    int*            pos   = (int*)  (ws + 402915328L);

    const size_t LDSR = 131072;   // router: 2 dbuf x (A 32K + B 32K)
    const size_t LDSE = 49152;    // experts: 2 dbuf x (A 8K + B 16K) -> 2 blk/CU

    // 1a) deduplicated split operands for router GEMM1
    split_x<<<NTOK, 256, 0, stream>>>(x, A2);
    {
        dim3 g(H_ / 32, C_ / 32, 1);
        split_w<<<g, 256, 0, stream>>>(rw1, B2);
    }
    // 1b) Router GEMM1 (split-bf16 exact, segment-remapped) + fused logits
    {
        dim3 g(H_ / 256, NTOK / 256, 1);
        gemm256_8ph<1, float, 3><<<g, 512, LDSR, stream>>>(
            A2, B2, rb1, (float*)nullptr, KR_, H_, KR_ / 64,
            4096, 4096, 4096, 2048, 0, 0, 0, 0, rw2, plog);
    }
    // 2) Deterministic final reduce + top-2 + softmax
    router_topk_final<<<NTOK / 256, 256, 0, stream>>>(plog, rb2, ids, probs);
    // 3) Exact sequential capacity positions
    compute_pos<<<1, 1024, 0, stream>>>(ids, pos);
    // 4) Dispatch tokens to expert buffers (bf16) — overwrites A2' (dead)
    dispatch_k<<<NSLOT, 256, 0, stream>>>(x, ids, pos, disp);
    // 5a) ew1 -> BT1 bf16
    {
        dim3 g(H_ / 32, C_ / 32, E_);
        transpose_cvt<<<g, 256, 0, stream>>>(ew1, BTW, C_, H_);
    }
    // 5b) Expert GEMM1, NEW 2-block/CU kernel: hexp = relu(disp @ ew1 + eb1)
    {
        dim3 g(H_ / 256, CAP_ / 128, E_);   // 16 x 32 x 8
        gemm128n<1, unsigned short><<<g, 256, LDSE, stream>>>(
            disp, BTW, eb1, hexp, C_, H_, C_ / 32,
            (long)CAP_ * C_, (long)H_ * C_, (long)H_, (long)CAP_ * H_);
    }
    // 6a) ew2 -> BT2 bf16
    {
        dim3 g(C_ / 32, H_ / 32, E_);
        transpose_cvt<<<g, 256, 0, stream>>>(ew2, BTW, H_, C_);
    }
    // 6b) Expert GEMM2, NEW kernel: eo = hexp @ ew2 + eb2
    {
        dim3 g(C_ / 256, CAP_ / 128, E_);   // 4 x 32 x 8
        gemm128n<0, unsigned short><<<g, 256, LDSE, stream>>>(
            hexp, BTW, eb2, eo, H_, C_, H_ / 32,
            (long)CAP_ * H_, (long)C_ * H_, (long)C_, (long)CAP_ * C_);
    }
    // 7) Combine: gather expert outputs, weight, sum (race-free)
    combine_k<<<NTOK, 256, 0, stream>>>(eo, ids, pos, probs, y);
}

// Round 19
// 1072.075 us; speedup vs baseline: 1.0629x; 1.0629x over previous
//
#include <hip/hip_runtime.h>
#include <cstdint>
#include <type_traits>

#define B_    8
#define T_    2048
#define C_    1024
#define E_    8
#define K_    2
#define CAP_  4096
#define H_    4096
#define NTOK  (B_ * T_)      // 16384
#define NSLOT (NTOK * K_)    // 32768
#define KR_   3072           // exact router split-GEMM K: [x_hi | x_lo | x_hi]

typedef __bf16 bf16x8 __attribute__((ext_vector_type(8)));
typedef float  f32x4  __attribute__((ext_vector_type(4)));

#define AS1 __attribute__((address_space(1)))
#define AS3 __attribute__((address_space(3)))

static __device__ __forceinline__ float b2f(unsigned short u) {
    union { float f; unsigned int i; } v; v.i = ((unsigned int)u) << 16; return v.f;
}
static __device__ __forceinline__ unsigned short f2b(float f) {
    unsigned int x = __float_as_uint(f);
    unsigned int r = (x + 0x7fffu + ((x >> 16) & 1u)) >> 16;   // RNE
    return (unsigned short)r;
}

template<int W> static __device__ __forceinline__ void vm_wait() {
    if constexpr (W == 4) asm volatile("s_waitcnt vmcnt(4)" ::: "memory");
    else if constexpr (W == 0) asm volatile("s_waitcnt vmcnt(0)" ::: "memory");
}

// ---------------------------------------------------------------------------
// 8-phase MFMA bf16 GEMM (round-9 proven schedule): 256x256 tile, BK=64,
// 512 threads (8 waves 2Mx4N, wave tile 128x64), 2 LDS dbufs (128 KiB).
// Counted vmcnt(4) never 0 mid-loop; round-9 hazard ledger.
// SEGMENT REMAP (round-17, data-identical): router K axis repeats segments;
// physical buffers store each once; stage source kb remapped (kb>=thr ->
// kb-thr, wave-uniform) -> bit-identical results.
// EPI=0: normal store. EPI=3: fused router-logits epilogue v2 (round-15):
// rw2 in REGISTERS, 2 shfl levels, 128KiB LDS pass, fixed-order sum ->
// plog[bx][n][8]. Deterministic; h1 never touches HBM.
// REFUTED levers (do not retry): launch_bounds min-waves 4 (r7 spill 6x);
// atomic combine (r13); approx+fixup (r12/13/16 neutral); smaller-tile
// 2-block/CU (r18: intensity loss > overlap gain); phase-ahead reads (r11
// neutral); 32x32 shape (r8 neutral + conflicts). MfmaUtil ~42% is this
// structure's wall (LDS BW ~= MFMA cycles at wave tile 128x64).
// ---------------------------------------------------------------------------
template<int RELU, typename TC, int EPI>
__global__ __launch_bounds__(512, 2) void gemm256_8ph(
    const unsigned short* __restrict__ A, const unsigned short* __restrict__ BT,
    const float* __restrict__ bias, TC* __restrict__ Cout,
    int Kd, int Nld, int NT,
    long rabA, long rabB,            // physical row strides (bytes) for A / BT
    long thrA, long thrB,            // segment-remap thresholds (bytes)
    long sA, long sB, long sBias, long sC,
    const float* __restrict__ rw2v, float* __restrict__ plogv)
{
    extern __shared__ char smem[];   // dbuf d: A at d*65536, B at d*65536+32768

    const int z = blockIdx.z;
    A    += (size_t)z * sA;
    BT   += (size_t)z * sB;
    bias += (size_t)z * sBias;
    if constexpr (EPI == 0) Cout += (size_t)z * sC;

    // XCD-aware swizzle (nwg % 8 == 0 for all our grids)
    const int gx = gridDim.x;
    const int nwg = gx * gridDim.y;
    int wg = blockIdx.y * gx + blockIdx.x;
    wg = (wg & 7) * (nwg >> 3) + (wg >> 3);
    const int bm = (wg / gx) * 256;
    const int bn = (wg % gx) * 256;

    const int tid  = threadIdx.x;
    const int lane = tid & 63;
    const int wid  = tid >> 6;
    const int wrow = (wid >> 2) * 128;   // wave M offset (2 waves in M)
    const int wcol = (wid & 3) * 64;     // wave N offset (4 waves in N)
    const int fr = lane & 15;            // fragment row/col within 16
    const int fq = lane >> 4;            // k-chunk selector (0..3)

    const char* Ag = (const char*)A  + (size_t)bm * rabA;
    const char* Bg = (const char*)BT + (size_t)bn * rabB;

    f32x4 acc[8][4];
#pragma unroll
    for (int i = 0; i < 8; i++)
#pragma unroll
        for (int j = 0; j < 4; j++) acc[i][j] = (f32x4){0.f, 0.f, 0.f, 0.f};

    auto STAGE_A = [&](int kt) {
        char* d = smem + (size_t)(kt & 1) * 65536;
        long kb = (long)kt * 128;
        if (kb >= thrA) kb -= thrA;          // segment remap (router A)
#pragma unroll
        for (int r = 0; r < 4; ++r) {
            const int o    = r * 8192 + tid * 16;
            const int row  = o >> 7;
            const int slot = (o >> 4) & 7;
            const int ss   = (slot ^ (row & 7)) << 4;
            __builtin_amdgcn_global_load_lds(
                (const AS1 void*)(Ag + (size_t)row * rabA + kb + ss),
                (AS3 void*)(d + r * 8192 + wid * 1024), 16, 0, 0);
        }
    };
    auto STAGE_B = [&](int kt) {
        char* d = smem + (size_t)(kt & 1) * 65536 + 32768;
        long kb = (long)kt * 128;
        if (kb >= thrB) kb -= thrB;          // segment remap (router B)
#pragma unroll
        for (int r = 0; r < 4; ++r) {
            const int o    = r * 8192 + tid * 16;
            const int row  = o >> 7;
            const int slot = (o >> 4) & 7;
            const int ss   = (slot ^ (row & 7)) << 4;
            __builtin_amdgcn_global_load_lds(
                (const AS1 void*)(Bg + (size_t)row * rabB + kb + ss),
                (AS3 void*)(d + r * 8192 + wid * 1024), 16, 0, 0);
        }
    };

    auto LDA = [&](int kt, int mi, int kk) -> bf16x8 {
        const char* base = smem + (size_t)(kt & 1) * 65536;
        const int row  = wrow + mi * 16 + fr;
        const int slot = (kk * 4 + fq) ^ (row & 7);
        return *(const bf16x8*)(base + row * 128 + slot * 16);
    };
    auto LDB = [&](int kt, int ni, int kk) -> bf16x8 {
        const char* base = smem + (size_t)(kt & 1) * 65536 + 32768;
        const int row  = wcol + ni * 16 + fr;
        const int slot = (kk * 4 + fq) ^ (row & 7);
        return *(const bf16x8*)(base + row * 128 + slot * 16);
    };

    // ---- prologue
    STAGE_A(0); STAGE_B(0); STAGE_B(1);
    vm_wait<4>();
    __builtin_amdgcn_s_barrier();

    bf16x8 a[4], bb[4];
    for (int kt = 0; kt < NT; ++kt) {
        // ---------- ph0
#pragma unroll
        for (int i = 0; i < 4; ++i) a[i]  = LDA(kt, i, 0);
#pragma unroll
        for (int i = 0; i < 4; ++i) bb[i] = LDB(kt, i, 0);
        if (kt + 1 < NT) STAGE_A(kt + 1);
        __builtin_amdgcn_s_barrier();
        __builtin_amdgcn_s_setprio(1);
#pragma unroll
        for (int mi = 0; mi < 4; ++mi)
#pragma unroll
            for (int ni = 0; ni < 4; ++ni)
                acc[mi][ni] = __builtin_amdgcn_mfma_f32_16x16x32_bf16(
                    a[mi], bb[ni], acc[mi][ni], 0, 0, 0);
        __builtin_amdgcn_s_setprio(0);
        __builtin_amdgcn_s_barrier();
        // ---------- ph1
#pragma unroll
        for (int i = 0; i < 4; ++i) a[i] = LDA(kt, 4 + i, 0);
        __builtin_amdgcn_s_barrier();
        __builtin_amdgcn_s_setprio(1);
#pragma unroll
        for (int mi = 0; mi < 4; ++mi)
#pragma unroll
            for (int ni = 0; ni < 4; ++ni)
                acc[4 + mi][ni] = __builtin_amdgcn_mfma_f32_16x16x32_bf16(
                    a[mi], bb[ni], acc[4 + mi][ni], 0, 0, 0);
        __builtin_amdgcn_s_setprio(0);
        __builtin_amdgcn_s_barrier();
        // ---------- ph2
#pragma unroll
        for (int i = 0; i < 4; ++i) a[i]  = LDA(kt, i, 1);
#pragma unroll
        for (int i = 0; i < 4; ++i) bb[i] = LDB(kt, i, 1);
        __builtin_amdgcn_s_barrier();
        __builtin_amdgcn_s_setprio(1);
#pragma unroll
        for (int mi = 0; mi < 4; ++mi)
#pragma unroll
            for (int ni = 0; ni < 4; ++ni)
                acc[mi][ni] = __builtin_amdgcn_mfma_f32_16x16x32_bf16(
                    a[mi], bb[ni], acc[mi][ni], 0, 0, 0);
        __builtin_amdgcn_s_setprio(0);
        __builtin_amdgcn_s_barrier();
        // ---------- ph3
#pragma unroll
        for (int i = 0; i < 4; ++i) a[i] = LDA(kt, 4 + i, 1);
        if (kt + 2 < NT) STAGE_B(kt + 2);
        if (kt + 1 < NT) {
            if (kt + 2 < NT) vm_wait<4>();
            else             vm_wait<0>();
        }
        __builtin_amdgcn_s_barrier();
        __builtin_amdgcn_s_setprio(1);
#pragma unroll
        for (int mi = 0; mi < 4; ++mi)
#pragma unroll
            for (int ni = 0; ni < 4; ++ni)
                acc[4 + mi][ni] = __builtin_amdgcn_mfma_f32_16x16x32_bf16(
                    a[mi], bb[ni], acc[4 + mi][ni], 0, 0, 0);
        __builtin_amdgcn_s_setprio(0);
        __builtin_amdgcn_s_barrier();
    }

    // ---- epilogue. 16x16 C/D map: col=lane&15, row=fq*4+reg (round-6 proven)
    const float* bias_o = bias;
    asm volatile("" : "+s"(bias_o));

    if constexpr (EPI == 3) {
        // rw2 slice in REGISTERS; smem reusable after final barrier (r14/r15).
        float w2r[4][8];
#pragma unroll
        for (int ni = 0; ni < 4; ++ni) {
            const float* src = rw2v + (size_t)(bn + wcol + ni * 16 + fr) * 8;
            *(float4*)(w2r[ni])     = *(const float4*)(src);
            *(float4*)(w2r[ni] + 4) = *(const float4*)(src + 4);
        }
        float bv[4];
#pragma unroll
        for (int ni = 0; ni < 4; ++ni)
            bv[ni] = bias_o[bn + wcol + ni * 16 + fr];

        float* pb = (float*)smem;    // pb[rowhalf2][colwave4][row128][frq4][e8]
        const int rowhalf = wid >> 2, colwave = wid & 3;
        const int frq = fr >> 2;

#pragma unroll
        for (int mi = 0; mi < 8; ++mi) {
#pragma unroll
            for (int rg = 0; rg < 4; ++rg) {
                float p[8];
#pragma unroll
                for (int e = 0; e < 8; ++e) p[e] = 0.f;
#pragma unroll
                for (int ni = 0; ni < 4; ++ni) {
                    const float h = fmaxf(acc[mi][ni][rg] + bv[ni], 0.f);
#pragma unroll
                    for (int e = 0; e < 8; ++e) p[e] = fmaf(h, w2r[ni][e], p[e]);
                }
#pragma unroll
                for (int e = 0; e < 8; ++e) {
                    p[e] += __shfl_xor(p[e], 1);
                    p[e] += __shfl_xor(p[e], 2);
                }
                if ((fr & 3) == 0) {
                    const int row = mi * 16 + fq * 4 + rg;   // 0..127 in-wave
                    float* dst = pb +
                        ((((size_t)rowhalf * 4 + colwave) * 128 + row) * 4 + frq) * 8;
                    *(float4*)(dst)     = make_float4(p[0], p[1], p[2], p[3]);
                    *(float4*)(dst + 4) = make_float4(p[4], p[5], p[6], p[7]);
                }
            }
        }
        __syncthreads();
        {
            const int r  = tid >> 1;
            const int eh = (tid & 1) * 4;
            const int rowhalf2 = r >> 7, rl = r & 127;
            float4 s = make_float4(0.f, 0.f, 0.f, 0.f);
#pragma unroll
            for (int cw = 0; cw < 4; ++cw)
#pragma unroll
                for (int q = 0; q < 4; ++q) {
                    const float4 v = *(const float4*)(pb +
                        ((((size_t)rowhalf2 * 4 + cw) * 128 + rl) * 4 + q) * 8 + eh);
                    s.x += v.x; s.y += v.y; s.z += v.z; s.w += v.w;
                }
            *(float4*)(plogv + ((size_t)(bn >> 8) * NTOK + bm + r) * 8 + eh) = s;
        }
    } else {
#pragma unroll
        for (int mi = 0; mi < 8; ++mi) {
#pragma unroll
            for (int ni = 0; ni < 4; ++ni) {
                const int c = bn + wcol + ni * 16 + fr;
                const float bv = bias_o[c];
#pragma unroll
                for (int rg = 0; rg < 4; ++rg) {
                    const int r = bm + wrow + mi * 16 + fq * 4 + rg;
                    float v = acc[mi][ni][rg] + bv;
                    if (RELU) v = fmaxf(v, 0.f);
                    if constexpr (std::is_same_v<TC, float>)
                        Cout[(size_t)r * Nld + c] = v;
                    else
                        Cout[(size_t)r * Nld + c] = f2b(v);
                }
            }
        }
    }
}

// ---------------------------------------------------------------------------
// Final router reduce: logits[n] = rb2 + sum_bx plog[bx][n][:] (fixed order,
// deterministic), then top-2 + softmax. One thread per token.
// ---------------------------------------------------------------------------
__global__ __launch_bounds__(256) void router_topk_final(
    const float* __restrict__ plog, const float* __restrict__ rb2,
    int* __restrict__ ids, float* __restrict__ probs)
{
    const int n = blockIdx.x * 256 + threadIdx.x;
    float l[E_];
#pragma unroll
    for (int e = 0; e < E_; ++e) l[e] = rb2[e];
#pragma unroll
    for (int bx = 0; bx < 16; ++bx) {
        const float4 a = *(const float4*)(plog + ((size_t)bx * NTOK + n) * 8);
        const float4 b = *(const float4*)(plog + ((size_t)bx * NTOK + n) * 8 + 4);
        l[0] += a.x; l[1] += a.y; l[2] += a.z; l[3] += a.w;
        l[4] += b.x; l[5] += b.y; l[6] += b.z; l[7] += b.w;
    }
    float v1 = -1e30f, v2 = -1e30f; int i1 = 0, i2 = 0;
#pragma unroll
    for (int e = 0; e < E_; ++e) {
        const float v = l[e];
        if (v > v1)      { v2 = v1; i2 = i1; v1 = v; i1 = e; }
        else if (v > v2) { v2 = v;  i2 = e; }
    }
    const float e2 = expf(v2 - v1);
    const float inv = 1.f / (1.f + e2);
    ids[n * 2] = i1;  ids[n * 2 + 1] = i2;
    probs[n * 2] = inv; probs[n * 2 + 1] = e2 * inv;
}

// ---------------------------------------------------------------------------
// Split x (fp32) -> A2' bf16 [NTOK][2048] = [x_hi | x_lo]
// ---------------------------------------------------------------------------
__global__ __launch_bounds__(256) void split_x(
    const float* __restrict__ x, unsigned short* __restrict__ A2)
{
    const int n = blockIdx.x;
    const int c = threadIdx.x * 4;
    const float4 v = *(const float4*)(x + (size_t)n * C_ + c);
    ushort4 hi, lo;
    hi.x = f2b(v.x); lo.x = f2b(v.x - b2f(hi.x));
    hi.y = f2b(v.y); lo.y = f2b(v.y - b2f(hi.y));
    hi.z = f2b(v.z); lo.z = f2b(v.z - b2f(hi.z));
    hi.w = f2b(v.w); lo.w = f2b(v.w - b2f(hi.w));
    unsigned short* row = A2 + (size_t)n * 2048;
    *(ushort4*)(row + c)        = hi;
    *(ushort4*)(row + C_ + c)   = lo;
}

// ---------------------------------------------------------------------------
// Split+transpose rw1 [C][H] fp32 -> B2' bf16 [H][2048] = [w_hi | w_lo]
// ---------------------------------------------------------------------------
__global__ __launch_bounds__(256) void split_w(
    const float* __restrict__ in, unsigned short* __restrict__ out)
{
    __shared__ float t[32][33];
    const int rb = blockIdx.y * 32;
    const int cb = blockIdx.x * 32;
    const int tr = threadIdx.x >> 3, tc = (threadIdx.x & 7) * 4;
    const float4 v = *(const float4*)(in + (size_t)(rb + tr) * H_ + cb + tc);
    t[tr][tc + 0] = v.x; t[tr][tc + 1] = v.y; t[tr][tc + 2] = v.z; t[tr][tc + 3] = v.w;
    __syncthreads();
    ushort4 hi, lo;
    float f;
    f = t[tc + 0][tr]; hi.x = f2b(f); lo.x = f2b(f - b2f(hi.x));
    f = t[tc + 1][tr]; hi.y = f2b(f); lo.y = f2b(f - b2f(hi.y));
    f = t[tc + 2][tr]; hi.z = f2b(f); lo.z = f2b(f - b2f(hi.z));
    f = t[tc + 3][tr]; hi.w = f2b(f); lo.w = f2b(f - b2f(hi.w));
    unsigned short* row = out + (size_t)(cb + tr) * 2048;
    *(ushort4*)(row + rb + tc)        = hi;
    *(ushort4*)(row + C_ + rb + tc)   = lo;
}

// ---------------------------------------------------------------------------
// Tiled transpose + fp32->bf16 convert: in [z][R][Ncols] f32 -> out [z][Ncols][R] bf16
// ---------------------------------------------------------------------------
__global__ __launch_bounds__(256) void transpose_cvt(
    const float* __restrict__ in, unsigned short* __restrict__ out, int R, int Ncols)
{
    __shared__ float t[32][33];
    const size_t zoff = (size_t)blockIdx.z * R * Ncols;
    in  += zoff;
    out += zoff;
    const int rb = blockIdx.y * 32, cb = blockIdx.x * 32;
    const int tr = threadIdx.x >> 3, tc = (threadIdx.x & 7) * 4;
    const float4 v = *(const float4*)(in + (size_t)(rb + tr) * Ncols + cb + tc);
    t[tr][tc + 0] = v.x; t[tr][tc + 1] = v.y; t[tr][tc + 2] = v.z; t[tr][tc + 3] = v.w;
    __syncthreads();
    ushort4 u;
    u.x = f2b(t[tc + 0][tr]); u.y = f2b(t[tc + 1][tr]);
    u.z = f2b(t[tc + 2][tr]); u.w = f2b(t[tc + 3][tr]);
    *(ushort4*)(out + (size_t)(cb + tr) * R + rb + tc) = u;
}

// ---------------------------------------------------------------------------
// Exact sequential per-expert prefix count (parallel scan, same semantics).
// ---------------------------------------------------------------------------
__global__ __launch_bounds__(1024) void compute_pos(
    const int* __restrict__ ids, int* __restrict__ pos)
{
    __shared__ int hist[1024][E_];   // 32 KiB
    const int t = threadIdx.x;
    const int per = NSLOT / 1024;    // 32
    int cnt[E_];
#pragma unroll
    for (int e = 0; e < E_; e++) cnt[e] = 0;
    const int s0 = t * per;
    for (int i = 0; i < per; i++) cnt[ids[s0 + i]]++;
#pragma unroll
    for (int e = 0; e < E_; e++) hist[t][e] = cnt[e];
    __syncthreads();
    const int wv = t >> 6, ln = t & 63;
    if (wv < E_) {
        const int e = wv;
        const int base = ln * 16;
        int vals[16];
        int s = 0;
#pragma unroll
        for (int i = 0; i < 16; i++) vals[i] = hist[base + i][e];
#pragma unroll
        for (int i = 0; i < 16; i++) { const int v = vals[i]; vals[i] = s; s += v; }
        int x = s;
        for (int d = 1; d < 64; d <<= 1) {
            const int y = __shfl_up(x, d);
            if (ln >= d) x += y;
        }
        const int excl = x - s;
#pragma unroll
        for (int i = 0; i < 16; i++) hist[base + i][e] = vals[i] + excl;
    }
    __syncthreads();
    int run[E_];
#pragma unroll
    for (int e = 0; e < E_; e++) run[e] = hist[t][e];
    for (int i = 0; i < per; i++) { const int e = ids[s0 + i]; pos[s0 + i] = run[e]++; }
}

// ---------------------------------------------------------------------------
// Dispatch: copy kept tokens into per-expert buffers (bf16).
// ---------------------------------------------------------------------------
__global__ __launch_bounds__(256) void dispatch_k(
    const float* __restrict__ x, const int* __restrict__ ids,
    const int* __restrict__ pos, unsigned short* __restrict__ disp)
{
    const int s = blockIdx.x;
    const int e = ids[s], p = pos[s];
    if (p >= CAP_) return;                      // dropped over capacity
    const int n = s >> 1;                       // K_ == 2
    const float4 v = *(const float4*)(x + (size_t)n * C_ + threadIdx.x * 4);
    ushort4 u;
    u.x = f2b(v.x); u.y = f2b(v.y); u.z = f2b(v.z); u.w = f2b(v.w);
    *(ushort4*)(disp + ((size_t)e * CAP_ + p) * C_ + threadIdx.x * 4) = u;
}

// ---------------------------------------------------------------------------
// Combine (gather, race-free): y[n] = sum_k probs * eo[id_k, pos_k]
// ---------------------------------------------------------------------------
__global__ __launch_bounds__(256) void combine_k(
    const unsigned short* __restrict__ eo, const int* __restrict__ ids,
    const int* __restrict__ pos, const float* __restrict__ probs,
    float* __restrict__ y)
{
    const int n = blockIdx.x;
    const int c = threadIdx.x * 4;
    float r0 = 0.f, r1 = 0.f, r2 = 0.f, r3 = 0.f;
#pragma unroll
    for (int k = 0; k < K_; k++) {
        const int p = pos[2 * n + k];
        if (p >= CAP_) continue;
        const int e = ids[2 * n + k];
        const float w = probs[2 * n + k];
        const ushort4 u = *(const ushort4*)(eo + ((size_t)e * CAP_ + p) * C_ + c);
        r0 = fmaf(w, b2f(u.x), r0); r1 = fmaf(w, b2f(u.y), r1);
        r2 = fmaf(w, b2f(u.z), r2); r3 = fmaf(w, b2f(u.w), r3);
    }
    *(float4*)(y + (size_t)n * C_ + c) = make_float4(r0, r1, r2, r3);
}

// ---------------------------------------------------------------------------
extern "C" void kernel_launch(void* const* d_in, const int* in_sizes, int n_in,
                              void* d_out, int out_size, void* d_ws, size_t ws_size,
                              hipStream_t stream)
{
    const float* x   = (const float*)d_in[0];
    const float* rw1 = (const float*)d_in[1];
    const float* rb1 = (const float*)d_in[2];
    const float* rw2 = (const float*)d_in[3];
    const float* rb2 = (const float*)d_in[4];
    const float* ew1 = (const float*)d_in[5];
    const float* eb1 = (const float*)d_in[6];
    const float* ew2 = (const float*)d_in[7];
    const float* eb2 = (const float*)d_in[8];
    float* y = (float*)d_out;

    // ws layout (round-17 evidenced):
    //  [0,256MiB)      hexp bf16 [8][4096][4096]
    //  [256,320MiB)    A2' bf16 [16384][2048] (router) -> later disp -> eo
    //  [320,384MiB)    BTW expert weights (written at 5a; A2'/B2'/plog dead)
    //  [352,360MiB)    B2' bf16 [4096][2048] (router; time-disjoint with BTW)
    //  [376,384MiB)    plog f32 [16][16384][8]
    //  [384MiB,...)    ids / probs / pos
    char* ws = (char*)d_ws;
    unsigned short* hexp  = (unsigned short*)ws;
    unsigned short* A2    = (unsigned short*)(ws + 268435456L);
    unsigned short* disp  = (unsigned short*)(ws + 268435456L);
    unsigned short* eo    = (unsigned short*)(ws + 268435456L);
    unsigned short* BTW   = (unsigned short*)(ws + 335544320L);
    unsigned short* B2    = (unsigned short*)(ws + 369098752L);
    float*          plog  = (float*)(ws + 394264576L);
    int*            ids   = (int*)  (ws + 402653184L);
    float*          probs = (float*)(ws + 402784256L);
    int*            pos   = (int*)  (ws + 402915328L);

    const size_t LDSB = 131072;   // 128 KiB: 2 dbuf x (A 32K + B 32K)
    const long HUGE_ = 1L << 60;

    // 1a) Build deduplicated split operands for router GEMM1
    split_x<<<NTOK, 256, 0, stream>>>(x, A2);
    {
        dim3 g(H_ / 32, C_ / 32, 1);
        split_w<<<g, 256, 0, stream>>>(rw1, B2);
    }
    // 1b) Router GEMM1 (split-bf16, ~fp32 exact, segment-remapped sources)
    //     + FUSED logits epilogue: plog[bx][n][8]; h1 never touches HBM.
    {
        dim3 g(H_ / 256, NTOK / 256, 1);   // 16 x 64
        gemm256_8ph<1, float, 3><<<g, 512, LDSB, stream>>>(
            A2, B2, rb1, (float*)nullptr, KR_, H_, KR_ / 64,
            4096 /*rabA*/, 4096 /*rabB*/, 4096 /*thrA*/, 2048 /*thrB*/,
            0, 0, 0, 0, rw2, plog);
    }
    // 2) Deterministic final reduce + top-2 + softmax
    router_topk_final<<<NTOK / 256, 256, 0, stream>>>(plog, rb2, ids, probs);
    // 3) Exact sequential capacity positions (parallel scan, same semantics)
    compute_pos<<<1, 1024, 0, stream>>>(ids, pos);
    // 4) Dispatch tokens to expert buffers (bf16) — overwrites A2' (dead)
    dispatch_k<<<NSLOT, 256, 0, stream>>>(x, ids, pos, disp);
    // 5a) Convert+transpose ew1 [8][1024][4096] -> BT1 bf16 [8][4096][1024]
    {
        dim3 g(H_ / 32, C_ / 32, E_);
        transpose_cvt<<<g, 256, 0, stream>>>(ew1, BTW, C_, H_);
    }
    // 5b) Expert GEMM1 (MFMA): hexp = relu(disp @ ew1 + eb1)
    {
        dim3 g(H_ / 256, CAP_ / 256, E_);   // 16 x 16 x 8
        gemm256_8ph<1, unsigned short, 0><<<g, 512, LDSB, stream>>>(
            disp, BTW, eb1, hexp, C_, H_, C_ / 64,
            (long)C_ * 2, (long)C_ * 2, HUGE_, HUGE_,
            (long)CAP_ * C_, (long)H_ * C_, (long)H_, (long)CAP_ * H_,
            nullptr, nullptr);
    }
    // 6a) Convert+transpose ew2 [8][4096][1024] -> BT2 bf16 [8][1024][4096]
    {
        dim3 g(C_ / 32, H_ / 32, E_);
        transpose_cvt<<<g, 256, 0, stream>>>(ew2, BTW, H_, C_);
    }
    // 6b) Expert GEMM2 (MFMA): eo = hexp @ ew2 + eb2   (bf16 out; disp dead)
    {
        dim3 g(C_ / 256, CAP_ / 256, E_);   // 4 x 16 x 8
        gemm256_8ph<0, unsigned short, 0><<<g, 512, LDSB, stream>>>(
            hexp, BTW, eb2, eo, H_, C_, H_ / 64,
            (long)H_ * 2, (long)H_ * 2, HUGE_, HUGE_,
            (long)CAP_ * H_, (long)C_ * H_, (long)C_, (long)CAP_ * C_,
            nullptr, nullptr);
    }
    // 7) Combine: gather expert outputs, weight, sum (race-free, writes all y)
    combine_k<<<NTOK, 256, 0, stream>>>(eo, ids, pos, probs, y);
}